// Round 1
// baseline (586.339 us; speedup 1.0000x reference)
//
#include <hip/hip_runtime.h>
#include <hip/hip_bf16.h>

#define NPTS 32768
#define NSLAB 16
#define NF 128
#define HDIM 128

// ---- workspace layout (bytes) ----
// [0, 64)           : g_count[16] (int)
// [1024, 1024+1MB)  : lists, u16 [16][NPTS]
// [2MB, 4MB)        : tau_all, f32 [16][NPTS]
// [4MB, 5MB)        : W2T, f32 [16][128][128]  (W2T[s][j][k] = W2[s][k][j])
#define WS_COUNT_OFF   0
#define WS_LIST_OFF    1024
#define WS_TAU_OFF     (2u << 20)
#define WS_W2T_OFF     (4u << 20)

__device__ __forceinline__ float fast_tanh(float v) {
    v = fminf(fmaxf(v, -15.0f), 15.0f);
    float t = __builtin_amdgcn_exp2f(v * 2.8853900817779268f); // e^{2v}
    return (t - 1.0f) * __builtin_amdgcn_rcpf(t + 1.0f);
}

__global__ void transpose_w2(const float* __restrict__ W2, float* __restrict__ W2T) {
    int s = blockIdx.y;
    int idx = blockIdx.x * 256 + threadIdx.x;        // 0..16383
    int k = idx >> 7, j = idx & 127;
    W2T[s * 16384 + j * 128 + k] = W2[s * 16384 + k * 128 + j];
}

__global__ void build_lists(const float* __restrict__ x,
                            const float* __restrict__ mids,
                            const float* __restrict__ widths,
                            int* __restrict__ g_count,
                            unsigned short* __restrict__ lists) {
    __shared__ int cnt[NSLAB];
    __shared__ int base[NSLAB];
    int tid = threadIdx.x;
    if (tid < NSLAB) cnt[tid] = 0;
    __syncthreads();
    int n = blockIdx.x * 256 + tid;
    float xc = x[n * 6];
    int ofs[NSLAB];
    unsigned int amask = 0;
    #pragma unroll
    for (int s = 0; s < NSLAB; ++s) {
        float xmin = mids[s] - 0.5f * widths[s];
        float xmax = mids[s] + 0.5f * widths[s];
        if (xc >= xmin && xc <= xmax) {
            ofs[s] = atomicAdd(&cnt[s], 1);
            amask |= (1u << s);
        }
    }
    __syncthreads();
    if (tid < NSLAB) base[tid] = atomicAdd(&g_count[tid], cnt[tid]);
    __syncthreads();
    #pragma unroll
    for (int s = 0; s < NSLAB; ++s)
        if (amask & (1u << s))
            lists[s * NPTS + base[s] + ofs[s]] = (unsigned short)n;
}

__global__ __launch_bounds__(256) void mlp_eval(
        const float* __restrict__ x,  const float* __restrict__ B,
        const float* __restrict__ W1, const float* __restrict__ b1,
        const float* __restrict__ W2T, const float* __restrict__ b2,
        const float* __restrict__ W3, const float* __restrict__ b3,
        const float* __restrict__ mids, const float* __restrict__ widths,
        const int* __restrict__ g_count,
        const unsigned short* __restrict__ lists,
        float* __restrict__ tau_all) {
    int s = blockIdx.y;
    int count = g_count[s];
    int i = blockIdx.x * 256 + threadIdx.x;
    if (i >= count) return;
    int n = lists[s * NPTS + i];

    float mid = mids[s], wd = widths[s];
    float xv[6];
    #pragma unroll
    for (int d = 0; d < 6; ++d) xv[d] = (x[n * 6 + d] - mid) / wd;

    const float* Bs  = B  + s * (NF * 3);
    const float* W1s = W1 + s * (4 * NF * HDIM);
    const float* b1s = b1 + s * HDIM;

    float h[HDIM];
    #pragma unroll
    for (int j = 0; j < HDIM; ++j) h[j] = b1s[j];

    for (int k = 0; k < NF; ++k) {
        float f0 = xv[0] * Bs[k * 3 + 0] + xv[1] * Bs[k * 3 + 1] + xv[2] * Bs[k * 3 + 2];
        float f1 = xv[3] * Bs[k * 3 + 0] + xv[4] * Bs[k * 3 + 1] + xv[5] * Bs[k * 3 + 2];
        // sin(2*pi*f) = v_sin(fract(f)) (hardware takes revolutions)
        float s0 = __builtin_amdgcn_sinf(__builtin_amdgcn_fractf(f0));
        float c0 = __builtin_amdgcn_cosf(__builtin_amdgcn_fractf(f0));
        float s1 = __builtin_amdgcn_sinf(__builtin_amdgcn_fractf(f1));
        float c1 = __builtin_amdgcn_cosf(__builtin_amdgcn_fractf(f1));
        const float* r0 = W1s + (k          ) * HDIM;
        const float* r1 = W1s + (NF     + k ) * HDIM;
        const float* r2 = W1s + (2 * NF + k ) * HDIM;
        const float* r3 = W1s + (3 * NF + k ) * HDIM;
        #pragma unroll
        for (int j = 0; j < HDIM; ++j)
            h[j] += s0 * r0[j] + c0 * r1[j] + s1 * r2[j] + c1 * r3[j];
    }
    #pragma unroll
    for (int j = 0; j < HDIM; ++j) h[j] = fast_tanh(h[j]);

    const float* W2s = W2T + s * (HDIM * HDIM); // [j][k]
    const float* b2s = b2 + s * HDIM;
    const float* W3s = W3 + s * HDIM;
    float tau = b3[s];
    for (int j = 0; j < HDIM; ++j) {
        const float* r = W2s + j * HDIM;
        float acc = b2s[j];
        #pragma unroll
        for (int k = 0; k < HDIM; ++k) acc += h[k] * r[k];
        tau += W3s[j] * fast_tanh(acc);
    }
    tau_all[s * NPTS + n] = tau;
}

__global__ void finalize(const float* __restrict__ x,
                         const float* __restrict__ mids,
                         const float* __restrict__ widths,
                         const float* __restrict__ tau_all,
                         float* __restrict__ out) {
    int n = blockIdx.x * 256 + threadIdx.x;
    if (n >= NPTS) return;
    float xc = x[n * 6];
    float num = 0.0f, den = 0.0f;
    #pragma unroll
    for (int s = 0; s < NSLAB; ++s) {
        float xmin = mids[s] - 0.5f * widths[s];
        float xmax = mids[s] + 0.5f * widths[s];
        if (xc >= xmin && xc <= xmax) {
            float xs = 2.0f * (xc - xmin) / (xmax - xmin) - 1.0f;
            // cos(pi*xs) = v_cos(fract(xs/2))
            float w = 0.5f * (1.0f + __builtin_amdgcn_cosf(__builtin_amdgcn_fractf(0.5f * xs)));
            num += w * tau_all[s * NPTS + n];
            den += w;
        }
    }
    out[n] = num / den;
}

extern "C" void kernel_launch(void* const* d_in, const int* in_sizes, int n_in,
                              void* d_out, int out_size, void* d_ws, size_t ws_size,
                              hipStream_t stream) {
    const float* x      = (const float*)d_in[0];
    const float* B      = (const float*)d_in[1];
    const float* W1     = (const float*)d_in[2];
    const float* b1     = (const float*)d_in[3];
    const float* W2     = (const float*)d_in[4];
    const float* b2     = (const float*)d_in[5];
    const float* W3     = (const float*)d_in[6];
    const float* b3     = (const float*)d_in[7];
    const float* mids   = (const float*)d_in[8];
    const float* widths = (const float*)d_in[9];
    float* out = (float*)d_out;

    char* ws = (char*)d_ws;
    int*            g_count = (int*)(ws + WS_COUNT_OFF);
    unsigned short* lists   = (unsigned short*)(ws + WS_LIST_OFF);
    float*          tau_all = (float*)(ws + WS_TAU_OFF);
    float*          W2T     = (float*)(ws + WS_W2T_OFF);

    hipMemsetAsync(g_count, 0, NSLAB * sizeof(int), stream);

    transpose_w2<<<dim3(64, NSLAB), 256, 0, stream>>>(W2, W2T);
    build_lists<<<dim3(NPTS / 256), 256, 0, stream>>>(x, mids, widths, g_count, lists);
    mlp_eval<<<dim3(NPTS / 256, NSLAB), 256, 0, stream>>>(
        x, B, W1, b1, W2T, b2, W3, b3, mids, widths, g_count, lists, tau_all);
    finalize<<<dim3(NPTS / 256), 256, 0, stream>>>(x, mids, widths, tau_all, out);
}